// Round 3
// baseline (250.030 us; speedup 1.0000x reference)
//
#include <hip/hip_runtime.h>
#include <math.h>

#define NVOXT 131072
#define NPIX  (370*1226)
#define NVAL  9554
#define DMT   16

// ---- workspace layout (bytes), total ~6.6 MB ----
#define OFF_INV    0                          // 25 doubles (invK 9, invE 16)
#define OFF_CNT    256                        // int count
#define OFF_MASK   512                        // int[131072]
#define OFF_LIST   (512 + 4*NVOXT)            // int[131072]
#define OFF_WCAT   (OFF_LIST + 4*NVOXT)       // f32[128*288]
#define OFF_BCAT   (OFF_WCAT + 4*128*288)     // f32[288]
#define OFF_VALUE  (OFF_BCAT + 4*288 + 128)   // f32[9554*128]

// ------------------------------------------------------------------
__device__ void gauss_inv(const float* A, double* out, int n) {
    double a[4][8];
    for (int r = 0; r < n; r++)
        for (int c = 0; c < n; c++) {
            a[r][c]     = (double)A[r*n + c];
            a[r][n + c] = (r == c) ? 1.0 : 0.0;
        }
    for (int col = 0; col < n; col++) {
        int piv = col; double best = fabs(a[col][col]);
        for (int r = col + 1; r < n; r++) {
            double m = fabs(a[r][col]);
            if (m > best) { best = m; piv = r; }
        }
        if (piv != col)
            for (int c = 0; c < 2*n; c++) { double t = a[col][c]; a[col][c] = a[piv][c]; a[piv][c] = t; }
        double dinv = 1.0 / a[col][col];
        for (int c = 0; c < 2*n; c++) a[col][c] *= dinv;
        for (int r = 0; r < n; r++) if (r != col) {
            double f = a[r][col];
            for (int c = 0; c < 2*n; c++) a[r][c] -= f * a[col][c];
        }
    }
    for (int r = 0; r < n; r++)
        for (int c = 0; c < n; c++) out[r*n + c] = a[r][n + c];
}

__global__ void setup_kernel(const float* Km, const float* Em,
                             const float* Woff, const float* Wattn,
                             const float* boff, const float* battn,
                             double* inv, float* wcat, float* bcat) {
    int t = threadIdx.x;
    if (t == 0) gauss_inv(Km, inv, 3);
    if (t == 1) gauss_inv(Em, inv + 9, 4);
    for (int flat = t; flat < 128*288; flat += 256) {
        int k = flat / 288, n = flat % 288;
        wcat[flat] = (n < 192) ? Woff[k*192 + n] : Wattn[k*96 + (n - 192)];
    }
    for (int n = t; n < 288; n += 256)
        bcat[n] = (n < 192) ? boff[n] : battn[n - 192];
}

__global__ void zero_kernel(int* mask, int* cnt) {
    int i = blockIdx.x * 256 + threadIdx.x;
    if (i < NVOXT) mask[i] = 0;
    if (i == 0) *cnt = 0;
}

// f32-emulated projection: inverses are f64-accurate rounded to f32, then
// all arithmetic follows the reference's f32 op order (trunc-boundary safety).
__global__ void mask_kernel(const float* depth, const float* org,
                            const double* invd, int* mask) {
    __shared__ float iK[9], iE[12];
    if (threadIdx.x < 9)  iK[threadIdx.x] = (float)invd[threadIdx.x];
    if (threadIdx.x < 12) iE[threadIdx.x] = (float)invd[9 + threadIdx.x];
    __syncthreads();
    int i = blockIdx.x * 256 + threadIdx.x;
    if (i >= NPIX) return;
    int u = i % 1226, v = i / 1226;
    float d  = depth[i];
    float px = (float)u * d, py = (float)v * d, pz = d;
    float c0 = iK[0]*px + iK[1]*py + iK[2]*pz;
    float c1 = iK[3]*px + iK[4]*py + iK[5]*pz;
    float c2 = iK[6]*px + iK[7]*py + iK[8]*pz;
    float w0 = iE[0]*c0 + iE[1]*c1 + iE[2]*c2  + iE[3];
    float w1 = iE[4]*c0 + iE[5]*c1 + iE[6]*c2  + iE[7];
    float w2 = iE[8]*c0 + iE[9]*c1 + iE[10]*c2 + iE[11];
    float q0 = truncf((w0 - org[0]) / 0.4f - 0.5f);
    float q1 = truncf((w1 - org[1]) / 0.4f - 0.5f);
    float q2 = truncf((w2 - org[2]) / 0.4f - 0.5f);
    if (q0 >= 0.0f && q0 < 128.0f && q1 >= 0.0f && q1 < 128.0f && q2 >= 0.0f && q2 < 8.0f) {
        int lin = (((int)q0) * 128 + (int)q1) * 8 + (int)q2;
        atomicOr(&mask[lin], 1);
    }
}

__global__ void compact_kernel(const int* mask, int* list, int* cnt) {
    int v = blockIdx.x * 256 + threadIdx.x;
    if (v < NVOXT && mask[v]) {
        int p = atomicAdd(cnt, 1);
        list[p] = v;
    }
}

__global__ void copy_kernel(const float4* src, float4* dst) {
    int i = blockIdx.x * 256 + threadIdx.x;
    dst[i] = src[i];
}

// ---- value = feat_flat @ W_val + b_val ; layout value[n][h*16+d] ----
__global__ __launch_bounds__(128) void value_kernel(
    const float* f0, const float* f1, const float* f2,
    const float* Wv, const float* bv, float* value) {
    __shared__ __align__(16) float As[16*129];
    int n0 = blockIdx.x * 16;
    int t  = threadIdx.x;
    for (int i = 0; i < 16; i++) {
        int flat = t + i*128;
        int k = flat >> 4, r = flat & 15;
        int n = n0 + r;
        float vload = 0.f;
        if (n < NVAL) {
            const float* f; int p, hw;
            if (n < 7238)      { f = f0; p = n;        hw = 7238; }
            else if (n < 9086) { f = f1; p = n - 7238; hw = 1848; }
            else               { f = f2; p = n - 9086; hw = 468;  }
            vload = f[k*hw + p];
        }
        As[r*129 + k] = vload;
    }
    __syncthreads();
    float acc[16];
    float bb = bv[t];
    #pragma unroll
    for (int r = 0; r < 16; r++) acc[r] = bb;
    for (int k = 0; k < 128; k++) {
        float w = Wv[k*128 + t];
        #pragma unroll
        for (int r = 0; r < 16; r++) acc[r] += As[r*129 + k] * w;
    }
    for (int r = 0; r < 16; r++) {
        int n = n0 + r;
        if (n < NVAL) value[n*128 + t] = acc[r];
    }
}

// NOTE: parameter must not be named x/y/z/w — it would substitute into the
// member accessors (.w) and break compilation (round-2 lesson).
#define FMA4(A, s, Vv) { A[0] += (s)*(Vv).x; A[1] += (s)*(Vv).y; A[2] += (s)*(Vv).z; A[3] += (s)*(Vv).w; }

// ---- deform: q->off/attn GEMM, softmax, bilinear gather, out-proj, LN1 ----
// LN1 output rows are staged IN d_out at the voxel's final location
// (row ownership is exclusive; ffn_kernel re-gathers and overwrites them).
__global__ __launch_bounds__(256) void deform_kernel(
    const float* scene, const float* refpix,
    const float* wcat, const float* bcat,
    const float* value, const float* Wout, const float* bout,
    const float* ln1g, const float* ln1b,
    const int* list, const int* cntp, float* out) {
    __shared__ __align__(16) float sQ[DMT*132];
    __shared__ __align__(16) float sW[9216];
    __shared__ __align__(16) float sOA[DMT*292];
    __shared__ __align__(16) float sSamp[DMT*132];

    const int count = *cntp;
    const int r0 = blockIdx.x * DMT;
    if (r0 >= count) return;
    const int t = threadIdx.x;

    // stage q rows (compact gather)
    for (int i = 0; i < 8; i++) {
        int flat = t + i*256;
        int m = flat >> 7, e = flat & 127;
        int r = r0 + m;
        float qv = 0.f;
        if (r < count) qv = scene[(size_t)list[r]*128 + e];
        sQ[m*132 + e] = qv;
    }
    __syncthreads();

    const int tn = t & 31, tm = t >> 5;       // rows {2tm, 2tm+1}, cols 4tn..4tn+3 (+n0)
    float acc[3][2][4] = {};

    // GEMM1: 16x128 @ 128x288 (k-chunks of 32)
    for (int c = 0; c < 4; c++) {
        __syncthreads();
        for (int i = 0; i < 36; i++) {
            int flat = t + i*256;
            sW[flat] = wcat[c*9216 + flat];
        }
        __syncthreads();
        for (int kk = 0; kk < 32; kk++) {
            int k = c*32 + kk;
            float a0 = sQ[(2*tm)*132 + k];
            float a1 = sQ[(2*tm+1)*132 + k];
            float4 w0 = *(const float4*)&sW[kk*288 + 4*tn];
            float4 w1 = *(const float4*)&sW[kk*288 + 128 + 4*tn];
            FMA4(acc[0][0], a0, w0); FMA4(acc[0][1], a1, w0);
            FMA4(acc[1][0], a0, w1); FMA4(acc[1][1], a1, w1);
            if (tn < 8) {
                float4 w2 = *(const float4*)&sW[kk*288 + 256 + 4*tn];
                FMA4(acc[2][0], a0, w2); FMA4(acc[2][1], a1, w2);
            }
        }
    }
    // write off/attn tile (+bias)
    for (int p = 0; p < 3; p++) {
        if (p == 2 && tn >= 8) continue;
        int nbase = p*128 + 4*tn;
        for (int i = 0; i < 2; i++)
            for (int j = 0; j < 4; j++)
                sOA[(2*tm+i)*292 + nbase + j] = acc[p][i][j] + bcat[nbase + j];
    }
    __syncthreads();

    // softmax + bilinear sampling: thread = (voxel v, head h, dim-half)
    {
        int v = t >> 4;
        int h = (t >> 1) & 7;
        int d0 = (t & 1) * 8;
        int r = r0 + v;
        int vox = (r < count) ? list[r] : list[0];
        float rx = refpix[vox*2 + 0], ry = refpix[vox*2 + 1];

        float L[12];
        float mx = -1e30f;
        #pragma unroll
        for (int j = 0; j < 12; j++) {
            L[j] = sOA[v*292 + 192 + h*12 + j];
            mx = fmaxf(mx, L[j]);
        }
        float s = 0.f;
        #pragma unroll
        for (int j = 0; j < 12; j++) { L[j] = expf(L[j] - mx); s += L[j]; }
        float inv_s = 1.f / s;

        const int   STl[3] = {0, 7238, 9086};
        const float FWl[3] = {154.f, 77.f, 39.f};
        const float FHl[3] = {47.f, 24.f, 12.f};

        float accA[4] = {0,0,0,0}, accB[4] = {0,0,0,0};
        for (int l = 0; l < 3; l++) {
            float fw = FWl[l], fh = FHl[l];
            int   st = STl[l];
            int   iw = (int)fw;
            for (int p = 0; p < 4; p++) {
                float ox = sOA[v*292 + h*24 + l*8 + p*2 + 0];
                float oy = sOA[v*292 + h*24 + l*8 + p*2 + 1];
                float x = rx*fw + ox - 0.5f;
                float y = ry*fh + oy - 0.5f;
                float aw = L[l*4 + p] * inv_s;
                float x0 = floorf(x), y0 = floorf(y);
                #pragma unroll
                for (int dy = 0; dy <= 1; dy++)
                #pragma unroll
                for (int dx = 0; dx <= 1; dx++) {
                    float xi = x0 + dx, yi = y0 + dy;
                    if (xi >= 0.f && xi <= fw - 1.f && yi >= 0.f && yi <= fh - 1.f) {
                        float cf = (1.f - fabsf(x - xi)) * (1.f - fabsf(y - yi)) * aw;
                        int idx = (int)yi * iw + (int)xi;
                        const float* vp = value + ((size_t)(st + idx)*128 + h*16 + d0);
                        float4 va = *(const float4*)vp;
                        float4 vb = *(const float4*)(vp + 4);
                        FMA4(accA, cf, va);
                        FMA4(accB, cf, vb);
                    }
                }
            }
        }
        float* sp = &sSamp[v*132 + h*16 + d0];
        *(float4*)sp       = make_float4(accA[0], accA[1], accA[2], accA[3]);
        *(float4*)(sp + 4) = make_float4(accB[0], accB[1], accB[2], accB[3]);
    }
    __syncthreads();

    // GEMM2: sampled @ W_out  (k-chunks of 64, reuse sW)
    float acc2[2][4] = {};
    for (int c = 0; c < 2; c++) {
        __syncthreads();
        for (int i = 0; i < 32; i++) {
            int flat = t + i*256;
            sW[flat] = Wout[c*8192 + flat];
        }
        __syncthreads();
        for (int kk = 0; kk < 64; kk++) {
            int k = c*64 + kk;
            float a0 = sSamp[(2*tm)*132 + k];
            float a1 = sSamp[(2*tm+1)*132 + k];
            float4 w = *(const float4*)&sW[kk*128 + 4*tn];
            FMA4(acc2[0], a0, w); FMA4(acc2[1], a1, w);
        }
    }
    __syncthreads();
    float* sX = sOA;   // reuse
    for (int i = 0; i < 2; i++)
        for (int j = 0; j < 4; j++) {
            int n = 4*tn + j, m = 2*tm + i;
            sX[m*132 + n] = acc2[i][j] + bout[n] + sQ[m*132 + n];
        }
    __syncthreads();

    // LN1 -> stage rows into d_out at final voxel location
    {
        int row = t >> 4, j16 = t & 15;
        float xs[8], s1 = 0.f, s2 = 0.f;
        #pragma unroll
        for (int q = 0; q < 8; q++) {
            float xv = sX[row*132 + j16*8 + q];
            xs[q] = xv; s1 += xv; s2 += xv*xv;
        }
        #pragma unroll
        for (int off = 8; off >= 1; off >>= 1) {
            s1 += __shfl_xor(s1, off, 16);
            s2 += __shfl_xor(s2, off, 16);
        }
        float mu  = s1 * (1.f/128.f);
        float var = s2 * (1.f/128.f) - mu*mu;
        float rs  = 1.f / sqrtf(var + 1e-5f);
        int r = r0 + row;
        if (r < count) {
            int vox = list[r];
            #pragma unroll
            for (int q = 0; q < 8; q++) {
                int e = j16*8 + q;
                out[(size_t)vox*128 + e] = (xs[q] - mu) * rs * ln1g[e] + ln1b[e];
            }
        }
    }
}

// ---- FFN: x -> 512 (gelu) -> 128, +x, LN2, scatter to out ----
__global__ __launch_bounds__(256) void ffn_kernel(
    const float* W1, const float* b1,
    const float* W2, const float* b2,
    const float* ln2g, const float* ln2b,
    const int* list, const int* cntp, float* out) {
    __shared__ __align__(16) float sX[DMT*132];
    __shared__ __align__(16) float sW[8192];
    __shared__ __align__(16) float sH[DMT*516];

    const int count = *cntp;
    const int r0 = blockIdx.x * DMT;
    if (r0 >= count) return;
    const int t = threadIdx.x;

    // gather LN1 rows (staged in d_out by deform_kernel)
    for (int i = 0; i < 8; i++) {
        int flat = t + i*256;
        int m = flat >> 7, e = flat & 127;
        int r = r0 + m;
        sX[m*132 + e] = (r < count) ? out[(size_t)list[r]*128 + e] : 0.f;
    }
    const int tn = t & 31, tm = t >> 5;

    // GEMM1 (4 n-passes of 128 over N=512), gelu
    for (int pass = 0; pass < 4; pass++) {
        int n0 = pass * 128;
        float acc[2][4] = {};
        for (int c = 0; c < 2; c++) {
            __syncthreads();
            for (int i = 0; i < 32; i++) {
                int flat = t + i*256;
                int kk = flat >> 7, col = flat & 127;
                sW[flat] = W1[(c*64 + kk)*512 + n0 + col];
            }
            __syncthreads();
            for (int kk = 0; kk < 64; kk++) {
                int k = c*64 + kk;
                float a0 = sX[(2*tm)*132 + k];
                float a1 = sX[(2*tm+1)*132 + k];
                float4 w = *(const float4*)&sW[kk*128 + 4*tn];
                FMA4(acc[0], a0, w); FMA4(acc[1], a1, w);
            }
        }
        for (int i = 0; i < 2; i++)
            for (int j = 0; j < 4; j++) {
                int n = n0 + 4*tn + j;
                float hv = acc[i][j] + b1[n];
                float g  = 0.5f * hv * (1.f + erff(hv * 0.70710678118654752f));
                sH[(2*tm+i)*516 + n] = g;
            }
    }

    // GEMM2: h(512) @ W2(512x128)
    float acc2[2][4] = {};
    for (int c = 0; c < 8; c++) {
        __syncthreads();
        for (int i = 0; i < 32; i++) {
            int flat = t + i*256;
            sW[flat] = W2[c*8192 + flat];
        }
        __syncthreads();
        for (int kk = 0; kk < 64; kk++) {
            int k = c*64 + kk;
            float a0 = sH[(2*tm)*516 + k];
            float a1 = sH[(2*tm+1)*516 + k];
            float4 w = *(const float4*)&sW[kk*128 + 4*tn];
            FMA4(acc2[0], a0, w); FMA4(acc2[1], a1, w);
        }
    }
    __syncthreads();
    float* sY = sH;   // reuse
    for (int i = 0; i < 2; i++)
        for (int j = 0; j < 4; j++) {
            int n = 4*tn + j, m = 2*tm + i;
            sY[m*132 + n] = acc2[i][j] + b2[n] + sX[m*132 + n];
        }
    __syncthreads();

    // LN2 + scatter
    {
        int row = t >> 4, j16 = t & 15;
        float ys[8], s1 = 0.f, s2 = 0.f;
        #pragma unroll
        for (int q = 0; q < 8; q++) {
            float yv = sY[row*132 + j16*8 + q];
            ys[q] = yv; s1 += yv; s2 += yv*yv;
        }
        #pragma unroll
        for (int off = 8; off >= 1; off >>= 1) {
            s1 += __shfl_xor(s1, off, 16);
            s2 += __shfl_xor(s2, off, 16);
        }
        float mu  = s1 * (1.f/128.f);
        float var = s2 * (1.f/128.f) - mu*mu;
        float rs  = 1.f / sqrtf(var + 1e-5f);
        int r = r0 + row;
        if (r < count) {
            int vox = list[r];
            #pragma unroll
            for (int q = 0; q < 8; q++) {
                int e = j16*8 + q;
                out[(size_t)vox*128 + e] = (ys[q] - mu) * rs * ln2g[e] + ln2b[e];
            }
        }
    }
}

extern "C" void kernel_launch(void* const* d_in, const int* in_sizes, int n_in,
                              void* d_out, int out_size, void* d_ws, size_t ws_size,
                              hipStream_t stream) {
    const float* scene  = (const float*)d_in[0];
    const float* feat0  = (const float*)d_in[1];
    const float* feat1  = (const float*)d_in[2];
    const float* feat2  = (const float*)d_in[3];
    const float* depth  = (const float*)d_in[4];
    const float* Km     = (const float*)d_in[5];
    const float* Em     = (const float*)d_in[6];
    const float* vorg   = (const float*)d_in[7];
    const float* refpix = (const float*)d_in[8];
    const float* W_off  = (const float*)d_in[9];
    const float* b_off  = (const float*)d_in[10];
    const float* W_attn = (const float*)d_in[11];
    const float* b_attn = (const float*)d_in[12];
    const float* W_val  = (const float*)d_in[13];
    const float* b_val  = (const float*)d_in[14];
    const float* W_out  = (const float*)d_in[15];
    const float* b_out  = (const float*)d_in[16];
    const float* ln1g   = (const float*)d_in[17];
    const float* ln1b   = (const float*)d_in[18];
    const float* W_ffn1 = (const float*)d_in[19];
    const float* b_ffn1 = (const float*)d_in[20];
    const float* W_ffn2 = (const float*)d_in[21];
    const float* b_ffn2 = (const float*)d_in[22];
    const float* ln2g   = (const float*)d_in[23];
    const float* ln2b   = (const float*)d_in[24];

    char* ws = (char*)d_ws;
    double* inv   = (double*)(ws + OFF_INV);
    int*    cnt   = (int*)   (ws + OFF_CNT);
    int*    mask  = (int*)   (ws + OFF_MASK);
    int*    list  = (int*)   (ws + OFF_LIST);
    float*  wcat  = (float*) (ws + OFF_WCAT);
    float*  bcat  = (float*) (ws + OFF_BCAT);
    float*  value = (float*) (ws + OFF_VALUE);
    float*  outp  = (float*)d_out;

    zero_kernel<<<513, 256, 0, stream>>>(mask, cnt);
    setup_kernel<<<1, 256, 0, stream>>>(Km, Em, W_off, W_attn, b_off, b_attn,
                                        inv, wcat, bcat);
    mask_kernel<<<1772, 256, 0, stream>>>(depth, vorg, inv, mask);
    compact_kernel<<<512, 256, 0, stream>>>(mask, list, cnt);
    value_kernel<<<598, 128, 0, stream>>>(feat0, feat1, feat2, W_val, b_val, value);
    copy_kernel<<<16384, 256, 0, stream>>>((const float4*)scene, (float4*)outp);
    deform_kernel<<<NVOXT/DMT, 256, 0, stream>>>(scene, refpix, wcat, bcat, value,
                                                 W_out, b_out, ln1g, ln1b,
                                                 list, cnt, outp);
    ffn_kernel<<<NVOXT/DMT, 256, 0, stream>>>(W_ffn1, b_ffn1, W_ffn2, b_ffn2,
                                              ln2g, ln2b, list, cnt, outp);
}

// Round 6
// 201.462 us; speedup vs baseline: 1.2411x; 1.2411x over previous
//
#include <hip/hip_runtime.h>
#include <math.h>

#define NVOXT 131072
#define NPIX  (370*1226)
#define NVAL  9554
#define DMT   16

// ---- workspace layout (bytes), total ~5.5 MB ----
#define OFF_INV    0                          // 25 doubles (invK 9, invE 16)
#define OFF_CNT    256                        // int count
#define OFF_MASK   512                        // int[131072]
#define OFF_LIST   (512 + 4*NVOXT)            // int[131072]
#define OFF_VALUE  (OFF_LIST + 4*NVOXT)       // f32[9554*128]

// ------------------------------------------------------------------
__device__ void gauss_inv(const float* A, double* out, int n) {
    double a[4][8];
    for (int r = 0; r < n; r++)
        for (int c = 0; c < n; c++) {
            a[r][c]     = (double)A[r*n + c];
            a[r][n + c] = (r == c) ? 1.0 : 0.0;
        }
    for (int col = 0; col < n; col++) {
        int piv = col; double best = fabs(a[col][col]);
        for (int r = col + 1; r < n; r++) {
            double m = fabs(a[r][col]);
            if (m > best) { best = m; piv = r; }
        }
        if (piv != col)
            for (int c = 0; c < 2*n; c++) { double t = a[col][c]; a[col][c] = a[piv][c]; a[piv][c] = t; }
        double dinv = 1.0 / a[col][col];
        for (int c = 0; c < 2*n; c++) a[col][c] *= dinv;
        for (int r = 0; r < n; r++) if (r != col) {
            double f = a[r][col];
            for (int c = 0; c < 2*n; c++) a[r][c] -= f * a[col][c];
        }
    }
    for (int r = 0; r < n; r++)
        for (int c = 0; c < n; c++) out[r*n + c] = a[r][n + c];
}

// zero mask + count; block 512 (past the mask range) computes the two
// matrix inverses on threads 0/1 — hidden under the other blocks' zeroing.
__global__ void zero_kernel(int* mask, int* cnt, const float* Km, const float* Em,
                            double* inv) {
    int i = blockIdx.x * 256 + threadIdx.x;
    if (i < NVOXT) mask[i] = 0;
    if (i == 0) *cnt = 0;
    if (blockIdx.x == 512) {
        if (threadIdx.x == 0) gauss_inv(Km, inv, 3);
        if (threadIdx.x == 1) gauss_inv(Em, inv + 9, 4);
    }
}

// f32-emulated projection: inverses are f64-accurate rounded to f32, then
// all arithmetic follows the reference's f32 op order (trunc-boundary safety).
__global__ void mask_kernel(const float* depth, const float* org,
                            const double* invd, int* mask) {
    __shared__ float iK[9], iE[12];
    if (threadIdx.x < 9)  iK[threadIdx.x] = (float)invd[threadIdx.x];
    if (threadIdx.x < 12) iE[threadIdx.x] = (float)invd[9 + threadIdx.x];
    __syncthreads();
    int i = blockIdx.x * 256 + threadIdx.x;
    if (i >= NPIX) return;
    int u = i % 1226, v = i / 1226;
    float d  = depth[i];
    float px = (float)u * d, py = (float)v * d, pz = d;
    float c0 = iK[0]*px + iK[1]*py + iK[2]*pz;
    float c1 = iK[3]*px + iK[4]*py + iK[5]*pz;
    float c2 = iK[6]*px + iK[7]*py + iK[8]*pz;
    float w0 = iE[0]*c0 + iE[1]*c1 + iE[2]*c2  + iE[3];
    float w1 = iE[4]*c0 + iE[5]*c1 + iE[6]*c2  + iE[7];
    float w2 = iE[8]*c0 + iE[9]*c1 + iE[10]*c2 + iE[11];
    float q0 = truncf((w0 - org[0]) / 0.4f - 0.5f);
    float q1 = truncf((w1 - org[1]) / 0.4f - 0.5f);
    float q2 = truncf((w2 - org[2]) / 0.4f - 0.5f);
    if (q0 >= 0.0f && q0 < 128.0f && q1 >= 0.0f && q1 < 128.0f && q2 >= 0.0f && q2 < 8.0f) {
        int lin = (((int)q0) * 128 + (int)q1) * 8 + (int)q2;
        atomicOr(&mask[lin], 1);
    }
}

__global__ void compact_kernel(const int* mask, int* list, int* cnt) {
    int v = blockIdx.x * 256 + threadIdx.x;
    if (v < NVOXT && mask[v]) {
        int p = atomicAdd(cnt, 1);
        list[p] = v;
    }
}

__global__ void copy_kernel(const float4* src, float4* dst) {
    int i = blockIdx.x * 256 + threadIdx.x;
    dst[i] = src[i];
}

// ---- value = feat_flat @ W_val + b_val ; layout value[n][h*16+d] ----
__global__ __launch_bounds__(128) void value_kernel(
    const float* f0, const float* f1, const float* f2,
    const float* Wv, const float* bv, float* value) {
    __shared__ __align__(16) float As[16*129];
    int n0 = blockIdx.x * 16;
    int t  = threadIdx.x;
    for (int i = 0; i < 16; i++) {
        int flat = t + i*128;
        int k = flat >> 4, r = flat & 15;
        int n = n0 + r;
        float vload = 0.f;
        if (n < NVAL) {
            const float* f; int p, hw;
            if (n < 7238)      { f = f0; p = n;        hw = 7238; }
            else if (n < 9086) { f = f1; p = n - 7238; hw = 1848; }
            else               { f = f2; p = n - 9086; hw = 468;  }
            vload = f[k*hw + p];
        }
        As[r*129 + k] = vload;
    }
    __syncthreads();
    float acc[16];
    float bb = bv[t];
    #pragma unroll
    for (int r = 0; r < 16; r++) acc[r] = bb;
    for (int k = 0; k < 128; k++) {
        float w = Wv[k*128 + t];
        #pragma unroll
        for (int r = 0; r < 16; r++) acc[r] += As[r*129 + k] * w;
    }
    for (int r = 0; r < 16; r++) {
        int n = n0 + r;
        if (n < NVAL) value[n*128 + t] = acc[r];
    }
}

// NOTE: parameter must not be named x/y/z/w — it would substitute into the
// member accessors (.w) and break compilation (round-2 lesson).
#define FMA4(A, s, Vv) { A[0] += (s)*(Vv).x; A[1] += (s)*(Vv).y; A[2] += (s)*(Vv).z; A[3] += (s)*(Vv).w; }

// ---- deform: q->off/attn GEMM, softmax, bilinear gather, out-proj, LN1 ----
// LN1 output rows are staged IN d_out at the voxel's final location
// (row ownership is exclusive; ffn_kernel re-gathers and overwrites them).
__global__ __launch_bounds__(256) void deform_kernel(
    const float* scene, const float* refpix,
    const float* Woff, const float* Wattn,
    const float* boff, const float* battn,
    const float* value, const float* Wout, const float* bout,
    const float* ln1g, const float* ln1b,
    const int* list, const int* cntp, float* out) {
    __shared__ __align__(16) float sQ[DMT*132];
    __shared__ __align__(16) float sW[9216];
    __shared__ __align__(16) float sOA[DMT*292];
    __shared__ __align__(16) float sSamp[DMT*132];

    const int count = *cntp;
    const int r0 = blockIdx.x * DMT;
    if (r0 >= count) return;
    const int t = threadIdx.x;

    // stage q rows (compact gather)
    for (int i = 0; i < 8; i++) {
        int flat = t + i*256;
        int m = flat >> 7, e = flat & 127;
        int r = r0 + m;
        float qv = 0.f;
        if (r < count) qv = scene[(size_t)list[r]*128 + e];
        sQ[m*132 + e] = qv;
    }
    __syncthreads();

    const int tn = t & 31, tm = t >> 5;       // rows {2tm, 2tm+1}, cols 4tn..4tn+3 (+n0)
    float acc[3][2][4] = {};

    // GEMM1: 16x128 @ 128x288 (k-chunks of 32); sW row kk holds
    // cols 0..191 = Woff[k], cols 192..287 = Wattn[k]
    for (int c = 0; c < 4; c++) {
        __syncthreads();
        for (int i = 0; i < 24; i++) {            // 32x192 off part
            int flat = t + i*256;
            int kk = flat / 192, n = flat % 192;
            sW[kk*288 + n] = Woff[(c*32 + kk)*192 + n];
        }
        for (int i = 0; i < 12; i++) {            // 32x96 attn part
            int flat = t + i*256;
            int kk = flat / 96, na = flat % 96;
            sW[kk*288 + 192 + na] = Wattn[(c*32 + kk)*96 + na];
        }
        __syncthreads();
        for (int kk = 0; kk < 32; kk++) {
            int k = c*32 + kk;
            float a0 = sQ[(2*tm)*132 + k];
            float a1 = sQ[(2*tm+1)*132 + k];
            float4 w0 = *(const float4*)&sW[kk*288 + 4*tn];
            float4 w1 = *(const float4*)&sW[kk*288 + 128 + 4*tn];
            FMA4(acc[0][0], a0, w0); FMA4(acc[0][1], a1, w0);
            FMA4(acc[1][0], a0, w1); FMA4(acc[1][1], a1, w1);
            if (tn < 8) {
                float4 w2 = *(const float4*)&sW[kk*288 + 256 + 4*tn];
                FMA4(acc[2][0], a0, w2); FMA4(acc[2][1], a1, w2);
            }
        }
    }
    // write off/attn tile (+bias, predicated select between the two arrays)
    for (int p = 0; p < 3; p++) {
        if (p == 2 && tn >= 8) continue;
        int nbase = p*128 + 4*tn;
        for (int i = 0; i < 2; i++)
            for (int j = 0; j < 4; j++) {
                int n = nbase + j;
                float bias = (n < 192) ? boff[n] : battn[n - 192];
                sOA[(2*tm+i)*292 + n] = acc[p][i][j] + bias;
            }
    }
    __syncthreads();

    // softmax + bilinear sampling: thread = (voxel v, head h, dim-half)
    {
        int v = t >> 4;
        int h = (t >> 1) & 7;
        int d0 = (t & 1) * 8;
        int r = r0 + v;
        int vox = (r < count) ? list[r] : list[0];
        float rx = refpix[vox*2 + 0], ry = refpix[vox*2 + 1];

        float L[12];
        float mx = -1e30f;
        #pragma unroll
        for (int j = 0; j < 12; j++) {
            L[j] = sOA[v*292 + 192 + h*12 + j];
            mx = fmaxf(mx, L[j]);
        }
        float s = 0.f;
        #pragma unroll
        for (int j = 0; j < 12; j++) { L[j] = expf(L[j] - mx); s += L[j]; }
        float inv_s = 1.f / s;

        const int   STl[3] = {0, 7238, 9086};
        const float FWl[3] = {154.f, 77.f, 39.f};
        const float FHl[3] = {47.f, 24.f, 12.f};

        float accA[4] = {0,0,0,0}, accB[4] = {0,0,0,0};
        for (int l = 0; l < 3; l++) {
            float fw = FWl[l], fh = FHl[l];
            int   st = STl[l];
            int   iw = (int)fw;
            for (int p = 0; p < 4; p++) {
                float ox = sOA[v*292 + h*24 + l*8 + p*2 + 0];
                float oy = sOA[v*292 + h*24 + l*8 + p*2 + 1];
                float x = rx*fw + ox - 0.5f;
                float y = ry*fh + oy - 0.5f;
                float aw = L[l*4 + p] * inv_s;
                float x0 = floorf(x), y0 = floorf(y);
                #pragma unroll
                for (int dy = 0; dy <= 1; dy++)
                #pragma unroll
                for (int dx = 0; dx <= 1; dx++) {
                    float xi = x0 + dx, yi = y0 + dy;
                    if (xi >= 0.f && xi <= fw - 1.f && yi >= 0.f && yi <= fh - 1.f) {
                        float cf = (1.f - fabsf(x - xi)) * (1.f - fabsf(y - yi)) * aw;
                        int idx = (int)yi * iw + (int)xi;
                        const float* vp = value + ((size_t)(st + idx)*128 + h*16 + d0);
                        float4 va = *(const float4*)vp;
                        float4 vb = *(const float4*)(vp + 4);
                        FMA4(accA, cf, va);
                        FMA4(accB, cf, vb);
                    }
                }
            }
        }
        float* sp = &sSamp[v*132 + h*16 + d0];
        *(float4*)sp       = make_float4(accA[0], accA[1], accA[2], accA[3]);
        *(float4*)(sp + 4) = make_float4(accB[0], accB[1], accB[2], accB[3]);
    }
    __syncthreads();

    // GEMM2: sampled @ W_out  (k-chunks of 64, reuse sW)
    float acc2[2][4] = {};
    for (int c = 0; c < 2; c++) {
        __syncthreads();
        for (int i = 0; i < 32; i++) {
            int flat = t + i*256;
            sW[flat] = Wout[c*8192 + flat];
        }
        __syncthreads();
        for (int kk = 0; kk < 64; kk++) {
            int k = c*64 + kk;
            float a0 = sSamp[(2*tm)*132 + k];
            float a1 = sSamp[(2*tm+1)*132 + k];
            float4 w = *(const float4*)&sW[kk*128 + 4*tn];
            FMA4(acc2[0], a0, w); FMA4(acc2[1], a1, w);
        }
    }
    __syncthreads();
    float* sX = sOA;   // reuse
    for (int i = 0; i < 2; i++)
        for (int j = 0; j < 4; j++) {
            int n = 4*tn + j, m = 2*tm + i;
            sX[m*132 + n] = acc2[i][j] + bout[n] + sQ[m*132 + n];
        }
    __syncthreads();

    // LN1 -> stage rows into d_out at final voxel location
    {
        int row = t >> 4, j16 = t & 15;
        float xs[8], s1 = 0.f, s2 = 0.f;
        #pragma unroll
        for (int q = 0; q < 8; q++) {
            float xv = sX[row*132 + j16*8 + q];
            xs[q] = xv; s1 += xv; s2 += xv*xv;
        }
        #pragma unroll
        for (int off = 8; off >= 1; off >>= 1) {
            s1 += __shfl_xor(s1, off, 16);
            s2 += __shfl_xor(s2, off, 16);
        }
        float mu  = s1 * (1.f/128.f);
        float var = s2 * (1.f/128.f) - mu*mu;
        float rs  = 1.f / sqrtf(var + 1e-5f);
        int r = r0 + row;
        if (r < count) {
            int vox = list[r];
            #pragma unroll
            for (int q = 0; q < 8; q++) {
                int e = j16*8 + q;
                out[(size_t)vox*128 + e] = (xs[q] - mu) * rs * ln1g[e] + ln1b[e];
            }
        }
    }
}

// ---- FFN: x -> 512 (gelu) -> 128, +x, LN2, scatter to out ----
__global__ __launch_bounds__(256) void ffn_kernel(
    const float* W1, const float* b1,
    const float* W2, const float* b2,
    const float* ln2g, const float* ln2b,
    const int* list, const int* cntp, float* out) {
    __shared__ __align__(16) float sX[DMT*132];
    __shared__ __align__(16) float sW[8192];
    __shared__ __align__(16) float sH[DMT*516];

    const int count = *cntp;
    const int r0 = blockIdx.x * DMT;
    if (r0 >= count) return;
    const int t = threadIdx.x;

    // gather LN1 rows (staged in d_out by deform_kernel)
    for (int i = 0; i < 8; i++) {
        int flat = t + i*256;
        int m = flat >> 7, e = flat & 127;
        int r = r0 + m;
        sX[m*132 + e] = (r < count) ? out[(size_t)list[r]*128 + e] : 0.f;
    }
    const int tn = t & 31, tm = t >> 5;

    // GEMM1 (4 n-passes of 128 over N=512), gelu
    for (int pass = 0; pass < 4; pass++) {
        int n0 = pass * 128;
        float acc[2][4] = {};
        for (int c = 0; c < 2; c++) {
            __syncthreads();
            for (int i = 0; i < 32; i++) {
                int flat = t + i*256;
                int kk = flat >> 7, col = flat & 127;
                sW[flat] = W1[(c*64 + kk)*512 + n0 + col];
            }
            __syncthreads();
            for (int kk = 0; kk < 64; kk++) {
                int k = c*64 + kk;
                float a0 = sX[(2*tm)*132 + k];
                float a1 = sX[(2*tm+1)*132 + k];
                float4 w = *(const float4*)&sW[kk*128 + 4*tn];
                FMA4(acc[0], a0, w); FMA4(acc[1], a1, w);
            }
        }
        for (int i = 0; i < 2; i++)
            for (int j = 0; j < 4; j++) {
                int n = n0 + 4*tn + j;
                float hv = acc[i][j] + b1[n];
                float g  = 0.5f * hv * (1.f + erff(hv * 0.70710678118654752f));
                sH[(2*tm+i)*516 + n] = g;
            }
    }

    // GEMM2: h(512) @ W2(512x128)
    float acc2[2][4] = {};
    for (int c = 0; c < 8; c++) {
        __syncthreads();
        for (int i = 0; i < 32; i++) {
            int flat = t + i*256;
            sW[flat] = W2[c*8192 + flat];
        }
        __syncthreads();
        for (int kk = 0; kk < 64; kk++) {
            int k = c*64 + kk;
            float a0 = sH[(2*tm)*516 + k];
            float a1 = sH[(2*tm+1)*516 + k];
            float4 w = *(const float4*)&sW[kk*128 + 4*tn];
            FMA4(acc2[0], a0, w); FMA4(acc2[1], a1, w);
        }
    }
    __syncthreads();
    float* sY = sH;   // reuse
    for (int i = 0; i < 2; i++)
        for (int j = 0; j < 4; j++) {
            int n = 4*tn + j, m = 2*tm + i;
            sY[m*132 + n] = acc2[i][j] + b2[n] + sX[m*132 + n];
        }
    __syncthreads();

    // LN2 + scatter
    {
        int row = t >> 4, j16 = t & 15;
        float ys[8], s1 = 0.f, s2 = 0.f;
        #pragma unroll
        for (int q = 0; q < 8; q++) {
            float yv = sY[row*132 + j16*8 + q];
            ys[q] = yv; s1 += yv; s2 += yv*yv;
        }
        #pragma unroll
        for (int off = 8; off >= 1; off >>= 1) {
            s1 += __shfl_xor(s1, off, 16);
            s2 += __shfl_xor(s2, off, 16);
        }
        float mu  = s1 * (1.f/128.f);
        float var = s2 * (1.f/128.f) - mu*mu;
        float rs  = 1.f / sqrtf(var + 1e-5f);
        int r = r0 + row;
        if (r < count) {
            int vox = list[r];
            #pragma unroll
            for (int q = 0; q < 8; q++) {
                int e = j16*8 + q;
                out[(size_t)vox*128 + e] = (ys[q] - mu) * rs * ln2g[e] + ln2b[e];
            }
        }
    }
}

extern "C" void kernel_launch(void* const* d_in, const int* in_sizes, int n_in,
                              void* d_out, int out_size, void* d_ws, size_t ws_size,
                              hipStream_t stream) {
    const float* scene  = (const float*)d_in[0];
    const float* feat0  = (const float*)d_in[1];
    const float* feat1  = (const float*)d_in[2];
    const float* feat2  = (const float*)d_in[3];
    const float* depth  = (const float*)d_in[4];
    const float* Km     = (const float*)d_in[5];
    const float* Em     = (const float*)d_in[6];
    const float* vorg   = (const float*)d_in[7];
    const float* refpix = (const float*)d_in[8];
    const float* W_off  = (const float*)d_in[9];
    const float* b_off  = (const float*)d_in[10];
    const float* W_attn = (const float*)d_in[11];
    const float* b_attn = (const float*)d_in[12];
    const float* W_val  = (const float*)d_in[13];
    const float* b_val  = (const float*)d_in[14];
    const float* W_out  = (const float*)d_in[15];
    const float* b_out  = (const float*)d_in[16];
    const float* ln1g   = (const float*)d_in[17];
    const float* ln1b   = (const float*)d_in[18];
    const float* W_ffn1 = (const float*)d_in[19];
    const float* b_ffn1 = (const float*)d_in[20];
    const float* W_ffn2 = (const float*)d_in[21];
    const float* b_ffn2 = (const float*)d_in[22];
    const float* ln2g   = (const float*)d_in[23];
    const float* ln2b   = (const float*)d_in[24];

    char* ws = (char*)d_ws;
    double* inv   = (double*)(ws + OFF_INV);
    int*    cnt   = (int*)   (ws + OFF_CNT);
    int*    mask  = (int*)   (ws + OFF_MASK);
    int*    list  = (int*)   (ws + OFF_LIST);
    float*  value = (float*) (ws + OFF_VALUE);
    float*  outp  = (float*)d_out;

    zero_kernel<<<513, 256, 0, stream>>>(mask, cnt, Km, Em, inv);
    mask_kernel<<<1772, 256, 0, stream>>>(depth, vorg, inv, mask);
    compact_kernel<<<512, 256, 0, stream>>>(mask, list, cnt);
    value_kernel<<<598, 128, 0, stream>>>(feat0, feat1, feat2, W_val, b_val, value);
    copy_kernel<<<16384, 256, 0, stream>>>((const float4*)scene, (float4*)outp);
    deform_kernel<<<NVOXT/DMT, 256, 0, stream>>>(scene, refpix, W_off, W_attn,
                                                 b_off, b_attn, value,
                                                 W_out, b_out, ln1g, ln1b,
                                                 list, cnt, outp);
    ffn_kernel<<<NVOXT/DMT, 256, 0, stream>>>(W_ffn1, b_ffn1, W_ffn2, b_ffn2,
                                              ln2g, ln2b, list, cnt, outp);
}

// Round 8
// 167.706 us; speedup vs baseline: 1.4909x; 1.2013x over previous
//
#include <hip/hip_runtime.h>
#include <math.h>

#define NVOXT 131072
#define NPIX  (370*1226)
#define NVAL  9554
#define DMT   16

// ---- workspace layout (bytes), total ~5.5 MB ----
#define OFF_INV    0                          // 25 doubles (invK 9, invE 16)
#define OFF_CNT    256                        // int count
#define OFF_MASK   512                        // int[131072]
#define OFF_LIST   (512 + 4*NVOXT)            // int[131072]
#define OFF_VALUE  (OFF_LIST + 4*NVOXT)       // f32[9554*128]

// ------------------------------------------------------------------
__device__ void gauss_inv(const float* A, double* out, int n) {
    double a[4][8];
    for (int r = 0; r < n; r++)
        for (int c = 0; c < n; c++) {
            a[r][c]     = (double)A[r*n + c];
            a[r][n + c] = (r == c) ? 1.0 : 0.0;
        }
    for (int col = 0; col < n; col++) {
        int piv = col; double best = fabs(a[col][col]);
        for (int r = col + 1; r < n; r++) {
            double m = fabs(a[r][col]);
            if (m > best) { best = m; piv = r; }
        }
        if (piv != col)
            for (int c = 0; c < 2*n; c++) { double t = a[col][c]; a[col][c] = a[piv][c]; a[piv][c] = t; }
        double dinv = 1.0 / a[col][col];
        for (int c = 0; c < 2*n; c++) a[col][c] *= dinv;
        for (int r = 0; r < n; r++) if (r != col) {
            double f = a[r][col];
            for (int c = 0; c < 2*n; c++) a[r][c] -= f * a[col][c];
        }
    }
    for (int r = 0; r < n; r++)
        for (int c = 0; c < n; c++) out[r*n + c] = a[r][n + c];
}

// ---- prologue: zero mask/cnt + matrix inverses + scene->out copy, one launch.
// blocks [0,512): zero mask (block 0 also inv + cnt); blocks [512,16896): copy.
__global__ void prologue_kernel(const float* Km, const float* Em, double* inv,
                                int* mask, int* cnt,
                                const float4* src, float4* dst) {
    int bid = blockIdx.x;
    if (bid < 512) {
        mask[bid*256 + threadIdx.x] = 0;
        if (bid == 0) {
            if (threadIdx.x == 64) *cnt = 0;          // separate wave from gauss
            if (threadIdx.x == 0) gauss_inv(Km, inv, 3);
            if (threadIdx.x == 1) gauss_inv(Em, inv + 9, 4);
        }
    } else {
        int i = (bid - 512)*256 + threadIdx.x;        // 16384 blocks -> 67 MB
        dst[i] = src[i];
    }
}

// f32-emulated projection (inverses f64-accurate, rounded to f32, then the
// reference's f32 op order — trunc-boundary safety). compact fused in:
// the first thread to set a voxel's mask bit appends it to list.
__global__ void mask_kernel(const float* depth, const float* org,
                            const double* invd, int* mask, int* list, int* cnt) {
    __shared__ float iK[9], iE[12];
    if (threadIdx.x < 9)  iK[threadIdx.x] = (float)invd[threadIdx.x];
    if (threadIdx.x < 12) iE[threadIdx.x] = (float)invd[9 + threadIdx.x];
    __syncthreads();
    int i = blockIdx.x * 256 + threadIdx.x;
    if (i >= NPIX) return;
    int u = i % 1226, v = i / 1226;
    float d  = depth[i];
    float px = (float)u * d, py = (float)v * d, pz = d;
    float c0 = iK[0]*px + iK[1]*py + iK[2]*pz;
    float c1 = iK[3]*px + iK[4]*py + iK[5]*pz;
    float c2 = iK[6]*px + iK[7]*py + iK[8]*pz;
    float w0 = iE[0]*c0 + iE[1]*c1 + iE[2]*c2  + iE[3];
    float w1 = iE[4]*c0 + iE[5]*c1 + iE[6]*c2  + iE[7];
    float w2 = iE[8]*c0 + iE[9]*c1 + iE[10]*c2 + iE[11];
    float q0 = truncf((w0 - org[0]) / 0.4f - 0.5f);
    float q1 = truncf((w1 - org[1]) / 0.4f - 0.5f);
    float q2 = truncf((w2 - org[2]) / 0.4f - 0.5f);
    if (q0 >= 0.0f && q0 < 128.0f && q1 >= 0.0f && q1 < 128.0f && q2 >= 0.0f && q2 < 8.0f) {
        int lin = (((int)q0) * 128 + (int)q1) * 8 + (int)q2;
        if (atomicOr(&mask[lin], 1) == 0) {
            int p = atomicAdd(cnt, 1);
            list[p] = lin;
        }
    }
}

// ---- value = feat_flat @ W_val + b_val ; layout value[n][h*16+d] ----
// Gated: when no voxel is masked, value is never consumed — skip the GEMM.
__global__ __launch_bounds__(128) void value_kernel(
    const float* f0, const float* f1, const float* f2,
    const float* Wv, const float* bv, const int* cntp, float* value) {
    if (*cntp == 0) return;
    __shared__ __align__(16) float As[16*129];
    int n0 = blockIdx.x * 16;
    int t  = threadIdx.x;
    for (int i = 0; i < 16; i++) {
        int flat = t + i*128;
        int k = flat >> 4, r = flat & 15;
        int n = n0 + r;
        float vload = 0.f;
        if (n < NVAL) {
            const float* f; int p, hw;
            if (n < 7238)      { f = f0; p = n;        hw = 7238; }
            else if (n < 9086) { f = f1; p = n - 7238; hw = 1848; }
            else               { f = f2; p = n - 9086; hw = 468;  }
            vload = f[k*hw + p];
        }
        As[r*129 + k] = vload;
    }
    __syncthreads();
    float acc[16];
    float bb = bv[t];
    #pragma unroll
    for (int r = 0; r < 16; r++) acc[r] = bb;
    for (int k = 0; k < 128; k++) {
        float w = Wv[k*128 + t];
        #pragma unroll
        for (int r = 0; r < 16; r++) acc[r] += As[r*129 + k] * w;
    }
    for (int r = 0; r < 16; r++) {
        int n = n0 + r;
        if (n < NVAL) value[n*128 + t] = acc[r];
    }
}

// NOTE: parameter must not be named x/y/z/w — it would substitute into the
// member accessors (.w) and break compilation (round-2 lesson).
#define FMA4(A, s, Vv) { A[0] += (s)*(Vv).x; A[1] += (s)*(Vv).y; A[2] += (s)*(Vv).z; A[3] += (s)*(Vv).w; }

// ---- deform: q->off/attn GEMM, softmax, bilinear gather, out-proj, LN1 ----
// Grid-stride over 16-row tiles (2048 blocks). LN1 rows staged IN d_out at the
// voxel's final location (exclusive row ownership; ffn re-gathers+overwrites).
// Cross-iteration LDS reuse is ordered by the existing in-body barriers.
__global__ __launch_bounds__(256) void deform_kernel(
    const float* scene, const float* refpix,
    const float* Woff, const float* Wattn,
    const float* boff, const float* battn,
    const float* value, const float* Wout, const float* bout,
    const float* ln1g, const float* ln1b,
    const int* list, const int* cntp, float* out) {
    __shared__ __align__(16) float sQ[DMT*132];
    __shared__ __align__(16) float sW[9216];
    __shared__ __align__(16) float sOA[DMT*292];
    __shared__ __align__(16) float sSamp[DMT*132];

    const int count = *cntp;
    const int t = threadIdx.x;
    const int tn = t & 31, tm = t >> 5;   // rows {2tm,2tm+1}, cols 4tn..4tn+3

    for (int r0 = blockIdx.x * DMT; r0 < count; r0 += gridDim.x * DMT) {

    // stage q rows (compact gather)
    for (int i = 0; i < 8; i++) {
        int flat = t + i*256;
        int m = flat >> 7, e = flat & 127;
        int r = r0 + m;
        float qv = 0.f;
        if (r < count) qv = scene[(size_t)list[r]*128 + e];
        sQ[m*132 + e] = qv;
    }
    __syncthreads();

    float acc[3][2][4] = {};

    // GEMM1: 16x128 @ 128x288 (k-chunks of 32); sW row kk holds
    // cols 0..191 = Woff[k], cols 192..287 = Wattn[k]
    for (int c = 0; c < 4; c++) {
        __syncthreads();
        for (int i = 0; i < 24; i++) {            // 32x192 off part
            int flat = t + i*256;
            int kk = flat / 192, n = flat % 192;
            sW[kk*288 + n] = Woff[(c*32 + kk)*192 + n];
        }
        for (int i = 0; i < 12; i++) {            // 32x96 attn part
            int flat = t + i*256;
            int kk = flat / 96, na = flat % 96;
            sW[kk*288 + 192 + na] = Wattn[(c*32 + kk)*96 + na];
        }
        __syncthreads();
        for (int kk = 0; kk < 32; kk++) {
            int k = c*32 + kk;
            float a0 = sQ[(2*tm)*132 + k];
            float a1 = sQ[(2*tm+1)*132 + k];
            float4 w0 = *(const float4*)&sW[kk*288 + 4*tn];
            float4 w1 = *(const float4*)&sW[kk*288 + 128 + 4*tn];
            FMA4(acc[0][0], a0, w0); FMA4(acc[0][1], a1, w0);
            FMA4(acc[1][0], a0, w1); FMA4(acc[1][1], a1, w1);
            if (tn < 8) {
                float4 w2 = *(const float4*)&sW[kk*288 + 256 + 4*tn];
                FMA4(acc[2][0], a0, w2); FMA4(acc[2][1], a1, w2);
            }
        }
    }
    // write off/attn tile (+bias, predicated select between the two arrays)
    for (int p = 0; p < 3; p++) {
        if (p == 2 && tn >= 8) continue;
        int nbase = p*128 + 4*tn;
        for (int i = 0; i < 2; i++)
            for (int j = 0; j < 4; j++) {
                int n = nbase + j;
                float bias = (n < 192) ? boff[n] : battn[n - 192];
                sOA[(2*tm+i)*292 + n] = acc[p][i][j] + bias;
            }
    }
    __syncthreads();

    // softmax + bilinear sampling: thread = (voxel v, head h, dim-half)
    {
        int v = t >> 4;
        int h = (t >> 1) & 7;
        int d0 = (t & 1) * 8;
        int r = r0 + v;
        int vox = (r < count) ? list[r] : list[0];
        float rx = refpix[vox*2 + 0], ry = refpix[vox*2 + 1];

        float L[12];
        float mx = -1e30f;
        #pragma unroll
        for (int j = 0; j < 12; j++) {
            L[j] = sOA[v*292 + 192 + h*12 + j];
            mx = fmaxf(mx, L[j]);
        }
        float s = 0.f;
        #pragma unroll
        for (int j = 0; j < 12; j++) { L[j] = expf(L[j] - mx); s += L[j]; }
        float inv_s = 1.f / s;

        const int   STl[3] = {0, 7238, 9086};
        const float FWl[3] = {154.f, 77.f, 39.f};
        const float FHl[3] = {47.f, 24.f, 12.f};

        float accA[4] = {0,0,0,0}, accB[4] = {0,0,0,0};
        for (int l = 0; l < 3; l++) {
            float fw = FWl[l], fh = FHl[l];
            int   st = STl[l];
            int   iw = (int)fw;
            for (int p = 0; p < 4; p++) {
                float ox = sOA[v*292 + h*24 + l*8 + p*2 + 0];
                float oy = sOA[v*292 + h*24 + l*8 + p*2 + 1];
                float x = rx*fw + ox - 0.5f;
                float y = ry*fh + oy - 0.5f;
                float aw = L[l*4 + p] * inv_s;
                float x0 = floorf(x), y0 = floorf(y);
                #pragma unroll
                for (int dy = 0; dy <= 1; dy++)
                #pragma unroll
                for (int dx = 0; dx <= 1; dx++) {
                    float xi = x0 + dx, yi = y0 + dy;
                    if (xi >= 0.f && xi <= fw - 1.f && yi >= 0.f && yi <= fh - 1.f) {
                        float cf = (1.f - fabsf(x - xi)) * (1.f - fabsf(y - yi)) * aw;
                        int idx = (int)yi * iw + (int)xi;
                        const float* vp = value + ((size_t)(st + idx)*128 + h*16 + d0);
                        float4 va = *(const float4*)vp;
                        float4 vb = *(const float4*)(vp + 4);
                        FMA4(accA, cf, va);
                        FMA4(accB, cf, vb);
                    }
                }
            }
        }
        float* sp = &sSamp[v*132 + h*16 + d0];
        *(float4*)sp       = make_float4(accA[0], accA[1], accA[2], accA[3]);
        *(float4*)(sp + 4) = make_float4(accB[0], accB[1], accB[2], accB[3]);
    }
    __syncthreads();

    // GEMM2: sampled @ W_out  (k-chunks of 64, reuse sW)
    float acc2[2][4] = {};
    for (int c = 0; c < 2; c++) {
        __syncthreads();
        for (int i = 0; i < 32; i++) {
            int flat = t + i*256;
            sW[flat] = Wout[c*8192 + flat];
        }
        __syncthreads();
        for (int kk = 0; kk < 64; kk++) {
            int k = c*64 + kk;
            float a0 = sSamp[(2*tm)*132 + k];
            float a1 = sSamp[(2*tm+1)*132 + k];
            float4 w = *(const float4*)&sW[kk*128 + 4*tn];
            FMA4(acc2[0], a0, w); FMA4(acc2[1], a1, w);
        }
    }
    __syncthreads();
    float* sX = sOA;   // reuse
    for (int i = 0; i < 2; i++)
        for (int j = 0; j < 4; j++) {
            int n = 4*tn + j, m = 2*tm + i;
            sX[m*132 + n] = acc2[i][j] + bout[n] + sQ[m*132 + n];
        }
    __syncthreads();

    // LN1 -> stage rows into d_out at final voxel location
    {
        int row = t >> 4, j16 = t & 15;
        float xs[8], s1 = 0.f, s2 = 0.f;
        #pragma unroll
        for (int q = 0; q < 8; q++) {
            float xv = sX[row*132 + j16*8 + q];
            xs[q] = xv; s1 += xv; s2 += xv*xv;
        }
        #pragma unroll
        for (int off = 8; off >= 1; off >>= 1) {
            s1 += __shfl_xor(s1, off, 16);
            s2 += __shfl_xor(s2, off, 16);
        }
        float mu  = s1 * (1.f/128.f);
        float var = s2 * (1.f/128.f) - mu*mu;
        float rs  = 1.f / sqrtf(var + 1e-5f);
        int r = r0 + row;
        if (r < count) {
            int vox = list[r];
            #pragma unroll
            for (int q = 0; q < 8; q++) {
                int e = j16*8 + q;
                out[(size_t)vox*128 + e] = (xs[q] - mu) * rs * ln1g[e] + ln1b[e];
            }
        }
    }

    } // grid-stride loop
}

// ---- FFN: x -> 512 (gelu) -> 128, +x, LN2, scatter to out (grid-stride) ----
__global__ __launch_bounds__(256) void ffn_kernel(
    const float* W1, const float* b1,
    const float* W2, const float* b2,
    const float* ln2g, const float* ln2b,
    const int* list, const int* cntp, float* out) {
    __shared__ __align__(16) float sX[DMT*132];
    __shared__ __align__(16) float sW[8192];
    __shared__ __align__(16) float sH[DMT*516];

    const int count = *cntp;
    const int t = threadIdx.x;
    const int tn = t & 31, tm = t >> 5;

    for (int r0 = blockIdx.x * DMT; r0 < count; r0 += gridDim.x * DMT) {

    // gather LN1 rows (staged in d_out by deform_kernel)
    for (int i = 0; i < 8; i++) {
        int flat = t + i*256;
        int m = flat >> 7, e = flat & 127;
        int r = r0 + m;
        sX[m*132 + e] = (r < count) ? out[(size_t)list[r]*128 + e] : 0.f;
    }

    // GEMM1 (4 n-passes of 128 over N=512), gelu
    for (int pass = 0; pass < 4; pass++) {
        int n0 = pass * 128;
        float acc[2][4] = {};
        for (int c = 0; c < 2; c++) {
            __syncthreads();
            for (int i = 0; i < 32; i++) {
                int flat = t + i*256;
                int kk = flat >> 7, col = flat & 127;
                sW[flat] = W1[(c*64 + kk)*512 + n0 + col];
            }
            __syncthreads();
            for (int kk = 0; kk < 64; kk++) {
                int k = c*64 + kk;
                float a0 = sX[(2*tm)*132 + k];
                float a1 = sX[(2*tm+1)*132 + k];
                float4 w = *(const float4*)&sW[kk*128 + 4*tn];
                FMA4(acc[0], a0, w); FMA4(acc[1], a1, w);
            }
        }
        for (int i = 0; i < 2; i++)
            for (int j = 0; j < 4; j++) {
                int n = n0 + 4*tn + j;
                float hv = acc[i][j] + b1[n];
                float g  = 0.5f * hv * (1.f + erff(hv * 0.70710678118654752f));
                sH[(2*tm+i)*516 + n] = g;
            }
    }

    // GEMM2: h(512) @ W2(512x128)
    float acc2[2][4] = {};
    for (int c = 0; c < 8; c++) {
        __syncthreads();
        for (int i = 0; i < 32; i++) {
            int flat = t + i*256;
            sW[flat] = W2[c*8192 + flat];
        }
        __syncthreads();
        for (int kk = 0; kk < 64; kk++) {
            int k = c*64 + kk;
            float a0 = sH[(2*tm)*516 + k];
            float a1 = sH[(2*tm+1)*516 + k];
            float4 w = *(const float4*)&sW[kk*128 + 4*tn];
            FMA4(acc2[0], a0, w); FMA4(acc2[1], a1, w);
        }
    }
    __syncthreads();
    float* sY = sH;   // reuse
    for (int i = 0; i < 2; i++)
        for (int j = 0; j < 4; j++) {
            int n = 4*tn + j, m = 2*tm + i;
            sY[m*132 + n] = acc2[i][j] + b2[n] + sX[m*132 + n];
        }
    __syncthreads();

    // LN2 + scatter
    {
        int row = t >> 4, j16 = t & 15;
        float ys[8], s1 = 0.f, s2 = 0.f;
        #pragma unroll
        for (int q = 0; q < 8; q++) {
            float yv = sY[row*132 + j16*8 + q];
            ys[q] = yv; s1 += yv; s2 += yv*yv;
        }
        #pragma unroll
        for (int off = 8; off >= 1; off >>= 1) {
            s1 += __shfl_xor(s1, off, 16);
            s2 += __shfl_xor(s2, off, 16);
        }
        float mu  = s1 * (1.f/128.f);
        float var = s2 * (1.f/128.f) - mu*mu;
        float rs  = 1.f / sqrtf(var + 1e-5f);
        int r = r0 + row;
        if (r < count) {
            int vox = list[r];
            #pragma unroll
            for (int q = 0; q < 8; q++) {
                int e = j16*8 + q;
                out[(size_t)vox*128 + e] = (ys[q] - mu) * rs * ln2g[e] + ln2b[e];
            }
        }
    }

    } // grid-stride loop
}

extern "C" void kernel_launch(void* const* d_in, const int* in_sizes, int n_in,
                              void* d_out, int out_size, void* d_ws, size_t ws_size,
                              hipStream_t stream) {
    const float* scene  = (const float*)d_in[0];
    const float* feat0  = (const float*)d_in[1];
    const float* feat1  = (const float*)d_in[2];
    const float* feat2  = (const float*)d_in[3];
    const float* depth  = (const float*)d_in[4];
    const float* Km     = (const float*)d_in[5];
    const float* Em     = (const float*)d_in[6];
    const float* vorg   = (const float*)d_in[7];
    const float* refpix = (const float*)d_in[8];
    const float* W_off  = (const float*)d_in[9];
    const float* b_off  = (const float*)d_in[10];
    const float* W_attn = (const float*)d_in[11];
    const float* b_attn = (const float*)d_in[12];
    const float* W_val  = (const float*)d_in[13];
    const float* b_val  = (const float*)d_in[14];
    const float* W_out  = (const float*)d_in[15];
    const float* b_out  = (const float*)d_in[16];
    const float* ln1g   = (const float*)d_in[17];
    const float* ln1b   = (const float*)d_in[18];
    const float* W_ffn1 = (const float*)d_in[19];
    const float* b_ffn1 = (const float*)d_in[20];
    const float* W_ffn2 = (const float*)d_in[21];
    const float* b_ffn2 = (const float*)d_in[22];
    const float* ln2g   = (const float*)d_in[23];
    const float* ln2b   = (const float*)d_in[24];

    char* ws = (char*)d_ws;
    double* inv   = (double*)(ws + OFF_INV);
    int*    cnt   = (int*)   (ws + OFF_CNT);
    int*    mask  = (int*)   (ws + OFF_MASK);
    int*    list  = (int*)   (ws + OFF_LIST);
    float*  value = (float*) (ws + OFF_VALUE);
    float*  outp  = (float*)d_out;

    prologue_kernel<<<16896, 256, 0, stream>>>(Km, Em, inv, mask, cnt,
                                               (const float4*)scene, (float4*)outp);
    mask_kernel<<<1772, 256, 0, stream>>>(depth, vorg, inv, mask, list, cnt);
    value_kernel<<<598, 128, 0, stream>>>(feat0, feat1, feat2, W_val, b_val,
                                          cnt, value);
    deform_kernel<<<2048, 256, 0, stream>>>(scene, refpix, W_off, W_attn,
                                            b_off, b_attn, value,
                                            W_out, b_out, ln1g, ln1b,
                                            list, cnt, outp);
    ffn_kernel<<<2048, 256, 0, stream>>>(W_ffn1, b_ffn1, W_ffn2, b_ffn2,
                                         ln2g, ln2b, list, cnt, outp);
}